// Round 8
// baseline (669.096 us; speedup 1.0000x reference)
//
#include <hip/hip_runtime.h>

typedef unsigned short ushort_t;
typedef unsigned short ushort8 __attribute__((ext_vector_type(8)));
typedef __bf16 bf16x8 __attribute__((ext_vector_type(8)));
typedef float f32x4 __attribute__((ext_vector_type(4)));
typedef unsigned int uint_t;

#define N_TOKENS 4096
#define D_MODEL  1024
#define D_HIDDEN 16384
#define TOPK     64
#define DELTA    0.03f   // >= 2*E, E = bf16-GEMM err (~5e-3) + bf16-Z quant (~4e-3)
#define RCAP     128     // max refine candidates per row (measured avg ~5)
#define T0SEL    1.25f   // candidate threshold; E[count]~249/row, v64~1.85 >> T0+DELTA
#define CAP      512     // candidate list capacity per row (E=249, sd~15)
#define SSL      15      // candidate slots per (row, 128-col segment); mean ~1.95

__device__ __forceinline__ float bf2f(ushort_t u) {
  union { unsigned u; float f; } c; c.u = ((unsigned)u) << 16; return c.f;
}
__device__ __forceinline__ ushort_t f2bf(float f) {
  union { float f; unsigned u; } c; c.f = f;
  unsigned x = c.u;
  unsigned r = (x + 0x7FFFu + ((x >> 16) & 1u)) >> 16;  // RNE
  return (ushort_t)r;
}

typedef __attribute__((address_space(1))) void GV;
typedef __attribute__((address_space(3))) void LV;
__device__ __forceinline__ void llds16(const void* g, void* l) {
  __builtin_amdgcn_global_load_lds((GV*)g, (LV*)l, 16, 0, 0);
}

// ---------------------------------------------------------------------------
// Kernel 0: cast x fp32 -> bf16
// ---------------------------------------------------------------------------
__global__ __launch_bounds__(256) void cast_x_kernel(
    const float* __restrict__ in, ushort_t* __restrict__ out) {
  const int i = (blockIdx.x * 256 + threadIdx.x) * 4;
  float4 v = *(const float4*)&in[i];
  ushort4 o;
  o.x = f2bf(v.x); o.y = f2bf(v.y); o.z = f2bf(v.z); o.w = f2bf(v.w);
  *(ushort4*)&out[i] = o;
}

// ---------------------------------------------------------------------------
// Kernel 0b: cast W_dec fp32 [H][K] -> bf16 (into WT buffer after last GEMM)
// ---------------------------------------------------------------------------
__global__ __launch_bounds__(256) void cast_wdec_kernel(
    const float* __restrict__ in, ushort_t* __restrict__ out) {
  const int i = (blockIdx.x * 256 + threadIdx.x) * 8;
  float4 v0 = *(const float4*)&in[i];
  float4 v1 = *(const float4*)&in[i + 4];
  ushort8 o;
  o[0] = f2bf(v0.x); o[1] = f2bf(v0.y); o[2] = f2bf(v0.z); o[3] = f2bf(v0.w);
  o[4] = f2bf(v1.x); o[5] = f2bf(v1.y); o[6] = f2bf(v1.z); o[7] = f2bf(v1.w);
  *(ushort8*)&out[i] = o;
}

// ---------------------------------------------------------------------------
// Kernel 1: W_enc fp32 [D_MODEL][D_HIDDEN] -> bf16 WT [H][K] + fp32 WT32 [H][K]
// ---------------------------------------------------------------------------
__global__ __launch_bounds__(256) void transpose_cast_kernel(
    const float* __restrict__ in, ushort_t* __restrict__ outb,
    float* __restrict__ out32) {
  __shared__ float tile[64][68];
  const int tid = threadIdx.x;
  const int n0 = blockIdx.x * 64;
  const int k0 = blockIdx.y * 64;
#pragma unroll
  for (int i = 0; i < 4; ++i) {
    int e = i * 256 + tid;
    int kk = e >> 4;
    int nn = (e & 15) * 4;
    float4 v = *(const float4*)&in[(size_t)(k0 + kk) * D_HIDDEN + n0 + nn];
    tile[kk][nn + 0] = v.x;
    tile[kk][nn + 1] = v.y;
    tile[kk][nn + 2] = v.z;
    tile[kk][nn + 3] = v.w;
  }
  __syncthreads();
#pragma unroll
  for (int i = 0; i < 4; ++i) {
    int e = i * 256 + tid;
    int nn = e >> 4;
    int kk = (e & 15) * 4;
    float4 f;
    f.x = tile[kk + 0][nn];
    f.y = tile[kk + 1][nn];
    f.z = tile[kk + 2][nn];
    f.w = tile[kk + 3][nn];
    *(float4*)&out32[(size_t)(n0 + nn) * D_MODEL + k0 + kk] = f;
    ushort4 b;
    b.x = f2bf(f.x); b.y = f2bf(f.y); b.z = f2bf(f.z); b.w = f2bf(f.w);
    *(ushort4*)&outb[(size_t)(n0 + nn) * D_MODEL + k0 + kk] = b;
  }
}

// ---------------------------------------------------------------------------
// Kernel 2 (R14): Z~ = relu(x @ W_enc + b_enc) + atomic-free candidate
// extraction. Main loop byte-identical to the verified 186us form.
// Epilogue: per-row LDS compaction (reusing As/Bs; per-row counters at 128
// distinct LDS addresses), then thread tid<128 writes ONE 64B cache line
// cand[row][cb] = {15 packed (bf16val<<16|lcol), count} that NO other block
// touches -> full-line exclusive writes, no global atomics (R11's +46us came
// from multi-block partial-line ping-pong; R9's +350us from per-value global
// atomics). Z still written (fallback input).
// ---------------------------------------------------------------------------
__global__ __launch_bounds__(256) void encode_gemm(
    const ushort_t* __restrict__ X, const ushort_t* __restrict__ WT,
    const float* __restrict__ benc, ushort_t* __restrict__ Z,
    uint_t* __restrict__ cand) {
  __shared__ ushort_t As[128 * 32];
  __shared__ ushort_t Bs[128 * 32];
  const int tid  = threadIdx.x;
  const int wave = tid >> 6, lane = tid & 63;
  const int m0 = blockIdx.y * 128;
  const int n0 = blockIdx.x * 128;
  const int wm = (wave >> 1) * 64;
  const int wn = (wave & 1) * 64;
  const int lr = lane >> 2;
  const int lk = (lane & 3) * 8;

  f32x4 acc[4][4];
#pragma unroll
  for (int i = 0; i < 4; ++i)
#pragma unroll
    for (int j = 0; j < 4; ++j) acc[i][j] = (f32x4){0.f, 0.f, 0.f, 0.f};

  for (int k0 = 0; k0 < D_MODEL; k0 += 32) {
    __syncthreads();
#pragma unroll
    for (int c = 0; c < 2; ++c) {
      const int chunk = c * 4 + wave;
      const int m = chunk * 16 + lr;
      llds16(&X [(size_t)(m0 + m) * D_MODEL + k0 + lk], &As[chunk * 512]);
      llds16(&WT[(size_t)(n0 + m) * D_MODEL + k0 + lk], &Bs[chunk * 512]);
    }
    __syncthreads();
    bf16x8 af[4], bfr[4];
#pragma unroll
    for (int t = 0; t < 4; ++t) {
      af[t]  = *(const bf16x8*)&As[(wm + t * 16 + (lane & 15)) * 32 + (lane >> 4) * 8];
      bfr[t] = *(const bf16x8*)&Bs[(wn + t * 16 + (lane & 15)) * 32 + (lane >> 4) * 8];
    }
#pragma unroll
    for (int mt = 0; mt < 4; ++mt)
#pragma unroll
      for (int nt = 0; nt < 4; ++nt)
        acc[mt][nt] = __builtin_amdgcn_mfma_f32_16x16x32_bf16(
            af[mt], bfr[nt], acc[mt][nt], 0, 0, 0);
  }

  // ---- epilogue: Z write + LDS candidate compaction (aliases As/Bs) ----
  uint_t* slots = (uint_t*)As;     // 128 rows x 15 slots x 4B = 7680B <= 8192B
  int*    lcnt  = (int*)Bs;        // 128 x 4B
  __syncthreads();                 // all waves done reading As/Bs
  if (tid < 128) lcnt[tid] = 0;
  __syncthreads();

  const int col_base  = n0 + wn + (lane & 15);
  const int lcol_base = wn + (lane & 15);
  const int row_base  = m0 + wm + (lane >> 4) * 4;
  const int lrow_base = wm + (lane >> 4) * 4;
#pragma unroll
  for (int nt = 0; nt < 4; ++nt) {
    const float bias = benc[col_base + nt * 16];
#pragma unroll
    for (int mt = 0; mt < 4; ++mt) {
#pragma unroll
      for (int r = 0; r < 4; ++r) {
        float v = fmaxf(acc[mt][nt][r] + bias, 0.0f);
        Z[(size_t)(row_base + mt * 16 + r) * D_HIDDEN + col_base + nt * 16] = f2bf(v);
        if (v > T0SEL) {
          const int lrw = lrow_base + mt * 16 + r;          // 0..127
          int p = atomicAdd(&lcnt[lrw], 1);
          if (p < SSL)
            slots[lrw * SSL + p] =
                ((uint_t)f2bf(v) << 16) | (uint_t)(lcol_base + nt * 16);
        }
      }
    }
  }
  __syncthreads();

  if (tid < 128) {
    const int c = lcnt[tid];                 // raw count; >SSL => poison
    const uint_t* s = &slots[tid * SSL];
    uint4 w0 = {s[0],  s[1],  s[2],  s[3]};
    uint4 w1 = {s[4],  s[5],  s[6],  s[7]};
    uint4 w2 = {s[8],  s[9],  s[10], s[11]};
    uint4 w3 = {s[12], s[13], s[14], (uint_t)c};
    uint_t* dst = cand + ((size_t)(m0 + tid) * 128 + blockIdx.x) * 16;
    ((uint4*)dst)[0] = w0;
    ((uint4*)dst)[1] = w1;
    ((uint4*)dst)[2] = w2;
    ((uint4*)dst)[3] = w3;
  }
}

// ---------------------------------------------------------------------------
// Kernel 3 (R14): select from the pre-filtered candidate lines. One block/row:
// reads 8KB of cand (not 128KB of Z), 2-wave count scan, scatter to LDS, then
// the VERBATIM verified machinery: exact v64 by (value desc, idx asc), DELTA
// band, fp64 refine via WT32. bf16 candidate values == Z-read semantics.
// Bails (flag=1) to the Z-based fallback on overflow / n<64 / n>CAP / v64
// near T0SEL (statistically never).
// ---------------------------------------------------------------------------
__global__ __launch_bounds__(256) void topk_select_kernel(
    const uint_t* __restrict__ cand, const float* __restrict__ x32,
    const float* __restrict__ WT32, const float* __restrict__ benc,
    float* __restrict__ vals, int* __restrict__ idxs, int* __restrict__ flags) {
  __shared__ float  sval[CAP];
  __shared__ int    sidx[CAP];
  __shared__ int    wsum[2];
  __shared__ int    ridx[RCAP];
  __shared__ double rex[RCAP];
  __shared__ float  sV64;
  __shared__ int    selCount, refCount, sOver;
  const int tid  = threadIdx.x;
  const int lane = tid & 63;
  const int wv   = tid >> 6;
  const int row  = blockIdx.x;

  // issue the candidate-line loads up front (tid<128: one 64B line each)
  uint4 e0, e1, e2, e3;
  if (tid < 128) {
    const uint_t* seg = cand + ((size_t)row * 128 + tid) * 16;
    e0 = ((const uint4*)seg)[0];
    e1 = ((const uint4*)seg)[1];
    e2 = ((const uint4*)seg)[2];
    e3 = ((const uint4*)seg)[3];
  }
  if (tid == 0) { selCount = 0; refCount = 0; sOver = 0; }
  __syncthreads();

  int myc = 0;
  if (tid < 128) {
    myc = (int)e3.w;
    if (myc > SSL) sOver = 1;     // lost candidates in this segment
  }
  const int valid = (tid < 128) ? min(myc, SSL) : 0;

  // inclusive scan within wave (waves 0,1 carry data; 2,3 idle)
  int inc = valid;
#pragma unroll
  for (int off = 1; off < 64; off <<= 1) {
    int y = __shfl_up(inc, off, 64);
    if (lane >= off) inc += y;
  }
  if (lane == 63 && wv < 2) wsum[wv] = inc;
  __syncthreads();
  const int base = inc - valid + ((wv == 1) ? wsum[0] : 0);
  const int n = wsum[0] + wsum[1];
  if (sOver || n < TOPK || n > CAP) { if (tid == 0) flags[row] = 1; return; }

  // scatter (static indices only — rule #20)
#define EMIT(k, pv)                                                       \
  if ((k) < valid) {                                                      \
    const uint_t p = (pv);                                                \
    const int q = base + (k);                                             \
    sval[q] = bf2f((ushort_t)(p >> 16));                                  \
    sidx[q] = (tid << 7) | (int)(p & 0x7Fu);                              \
  }
  if (tid < 128) {
    EMIT(0, e0.x)  EMIT(1, e0.y)  EMIT(2, e0.z)  EMIT(3, e0.w)
    EMIT(4, e1.x)  EMIT(5, e1.y)  EMIT(6, e1.z)  EMIT(7, e1.w)
    EMIT(8, e2.x)  EMIT(9, e2.y)  EMIT(10, e2.z) EMIT(11, e2.w)
    EMIT(12, e3.x) EMIT(13, e3.y) EMIT(14, e3.z)
  }
#undef EMIT
  __syncthreads();

  // ---- exact 64th by (value desc, index asc); LDS reads are broadcasts ----
  for (int j = tid; j < n; j += 256) {
    float vj = sval[j]; int ij = sidx[j];
    int rank = 0;
    for (int j2 = 0; j2 < n; ++j2) {
      float v2 = sval[j2];
      rank += (v2 > vj) || (v2 == vj && sidx[j2] < ij);
    }
    if (rank == TOPK - 1) sV64 = vj;
  }
  __syncthreads();
  const float v64 = sV64;
  if (v64 <= T0SEL + DELTA) { if (tid == 0) flags[row] = 1; return; }

  // ---- classify: sure-selects vs refine band ----
  for (int j = tid; j < n; j += 256) {
    float v = sval[j];
    if (v > v64 + DELTA) {
      int p2 = atomicAdd(&selCount, 1);
      vals[(size_t)row * TOPK + p2] = v;
      idxs[(size_t)row * TOPK + p2] = sidx[j];
    } else if (v >= v64 - DELTA) {
      int c = atomicAdd(&refCount, 1);
      if (c < RCAP) ridx[c] = sidx[j];
    }
  }
  __syncthreads();
  if (refCount > RCAP) { if (tid == 0) flags[row] = 1; return; }
  if (tid == 0) flags[row] = 0;
  const int nS = selCount;
  const int nR = refCount;
  const int rNeed = TOPK - nS;

  // ---- Phase D: exact fp64 dots, one wave per candidate ----
  float xr[16];
  {
    const float* xrb = &x32[(size_t)row * D_MODEL + lane * 16];
#pragma unroll
    for (int q = 0; q < 4; ++q)
      *(float4*)&xr[q * 4] = *(const float4*)&xrb[q * 4];
  }
  for (int c = wv; c < nR; c += 4) {
    const int j = ridx[c];
    const float* wr = &WT32[(size_t)j * D_MODEL];
    double p0 = 0.0, p1 = 0.0;
#pragma unroll
    for (int q = 0; q < 2; ++q) {
      const float4 wa = *(const float4*)&wr[lane * 16 + q * 8];
      const float4 wb = *(const float4*)&wr[lane * 16 + q * 8 + 4];
      p0 += (double)xr[q * 8 + 0] * wa.x + (double)xr[q * 8 + 1] * wa.y
          + (double)xr[q * 8 + 2] * wa.z + (double)xr[q * 8 + 3] * wa.w;
      p1 += (double)xr[q * 8 + 4] * wb.x + (double)xr[q * 8 + 5] * wb.y
          + (double)xr[q * 8 + 6] * wb.z + (double)xr[q * 8 + 7] * wb.w;
    }
    double part = p0 + p1;
#pragma unroll
    for (int off = 32; off > 0; off >>= 1) part += __shfl_down(part, off, 64);
    if (lane == 0) {
      double d = part + (double)benc[j];
      rex[c] = d > 0.0 ? d : 0.0;
    }
  }
  __syncthreads();

  // ---- Phase E: rank refined by (value desc, index asc), take top rNeed ----
  for (int c = tid; c < nR; c += 256) {
    double vc = rex[c]; int ic = ridx[c];
    int rank = 0;
    for (int c2 = 0; c2 < nR; ++c2) {
      double v2 = rex[c2];
      rank += (v2 > vc) || (v2 == vc && ridx[c2] < ic);
    }
    if (rank < rNeed) {
      int p2 = atomicAdd(&selCount, 1);
      vals[(size_t)row * TOPK + p2] = (float)vc;
      idxs[(size_t)row * TOPK + p2] = ic;
    }
  }
}

// ---------------------------------------------------------------------------
// Kernel 3b: fallback — full-row top-64 from bf16 Z (verbatim verified path),
// runs only for flagged rows (statistically never; correctness insurance).
// ---------------------------------------------------------------------------
__global__ __launch_bounds__(256) void topk_fallback_kernel(
    const int* __restrict__ flags,
    const ushort_t* __restrict__ Z, const float* __restrict__ x32,
    const float* __restrict__ WT32, const float* __restrict__ benc,
    float* __restrict__ vals, int* __restrict__ idxs) {
  if (flags[blockIdx.x] == 0) return;
  __shared__ int hist[512 * 9 + 32];
  float*  cval = (float*)hist;                 // [512]
  int*    cidx = (int*)hist + 512;             // [512]
  int*    ridx = (int*)hist + 1024;            // [RCAP]
  double* rex  = (double*)((int*)hist + 1156); // [RCAP]
  __shared__ int   wtot[4];
  __shared__ int   sTbin, sAbove, selCount, candCount, refCount;
  __shared__ float sV64;

  const int tid  = threadIdx.x;
  const int wave = tid >> 6, lane = tid & 63;
  const int row  = blockIdx.x;
  const ushort_t* zr = Z + (size_t)row * D_HIDDEN;

  ushort8 u8v[8];
#pragma unroll
  for (int i = 0; i < 8; ++i) u8v[i] = *(const ushort8*)&zr[i * 2048 + tid * 8];
#define ZIDX(i, j) ((i) * 2048 + tid * 8 + (j))

  for (int k = tid; k < 512 * 9; k += 256) hist[k] = 0;
  if (tid == 0) { sTbin = -1; selCount = 0; candCount = 0; refCount = 0; }
  __syncthreads();

  const int cpy = lane & 7;
#pragma unroll
  for (int i = 0; i < 8; ++i)
#pragma unroll
    for (int j = 0; j < 8; ++j) {
      ushort_t w = u8v[i][j];
      if (w) atomicAdd(&hist[((int)(w >> 6)) * 9 + cpy], 1);
    }
  __syncthreads();

  int h0 = 0, h1 = 0;
#pragma unroll
  for (int c = 0; c < 8; ++c) {
    int cc = (tid + c) & 7;
    h0 += hist[(2 * tid) * 9 + cc];
    h1 += hist[(2 * tid + 1) * 9 + cc];
  }
  const int s = h0 + h1;
  int x = s;
#pragma unroll
  for (int off = 1; off < 64; off <<= 1) {
    int y = __shfl_down(x, off, 64);
    if (lane + off < 64) x += y;
  }
  if (lane == 0) wtot[wave] = x;
  __syncthreads();
  int cross = 0;
  if (wave < 3) cross += wtot[3];
  if (wave < 2) cross += wtot[2];
  if (wave < 1) cross += wtot[1];
  const int Sexc = cross + x - s;
  if (Sexc < TOPK && Sexc + h1 >= TOPK) { sTbin = 2 * tid + 1; sAbove = Sexc; }
  const int c0 = Sexc + h1;
  if (c0 < TOPK && c0 + h0 >= TOPK) { sTbin = 2 * tid; sAbove = c0; }
  __syncthreads();
  const int Tbin = sTbin, nAbove = sAbove;

  if (Tbin < 0) {
#pragma unroll
    for (int i = 0; i < 8; ++i)
#pragma unroll
      for (int j = 0; j < 8; ++j) {
        ushort_t w = u8v[i][j];
        if (w) {
          int p = atomicAdd(&selCount, 1);
          if (p < TOPK) { vals[row * 64 + p] = bf2f(w); idxs[row * 64 + p] = ZIDX(i, j); }
        }
      }
    __syncthreads();
    for (int p2 = min(selCount, TOPK) + tid; p2 < TOPK; p2 += 256) {
      vals[row * 64 + p2] = 0.0f; idxs[row * 64 + p2] = 0;
    }
    return;
  }

#pragma unroll
  for (int i = 0; i < 8; ++i)
#pragma unroll
    for (int j = 0; j < 8; ++j) {
      ushort_t w = u8v[i][j];
      if (w && (int)(w >> 6) == Tbin) {
        int c = atomicAdd(&candCount, 1);
        if (c < 512) { cval[c] = bf2f(w); cidx[c] = ZIDX(i, j); }
      }
    }
  __syncthreads();
  {
    const int r  = TOPK - nAbove;
    const int nc = min(candCount, 512);
    for (int j = tid; j < nc; j += 256) {
      float vj = cval[j]; int ij = cidx[j];
      int rank = 0;
      for (int j2 = 0; j2 < nc; ++j2) {
        float v2 = cval[j2];
        rank += (v2 > vj) || (v2 == vj && cidx[j2] < ij);
      }
      if (rank == r - 1) sV64 = vj;
    }
  }
  __syncthreads();
  const float v64 = sV64;

#pragma unroll
  for (int i = 0; i < 8; ++i)
#pragma unroll
    for (int j = 0; j < 8; ++j) {
      ushort_t w = u8v[i][j];
      if (!w) continue;
      float v = bf2f(w);
      if (v > v64 + DELTA) {
        int p = atomicAdd(&selCount, 1);
        vals[row * 64 + p] = v;
        idxs[row * 64 + p] = ZIDX(i, j);
      } else if (v >= v64 - DELTA) {
        int c = atomicAdd(&refCount, 1);
        if (c < RCAP) ridx[c] = ZIDX(i, j);
      }
    }
  __syncthreads();
  const int nS = selCount;
  const int nR = min(refCount, RCAP);
  const int rNeed = TOPK - nS;

  float xr[16];
  {
    const float* xrb = &x32[(size_t)row * D_MODEL + lane * 16];
#pragma unroll
    for (int q = 0; q < 4; ++q)
      *(float4*)&xr[q * 4] = *(const float4*)&xrb[q * 4];
  }
  for (int c = wave; c < nR; c += 4) {
    const int j = ridx[c];
    const float* wr = &WT32[(size_t)j * D_MODEL];
    double p0 = 0.0, p1 = 0.0;
#pragma unroll
    for (int q = 0; q < 2; ++q) {
      const float4 wa = *(const float4*)&wr[lane * 16 + q * 8];
      const float4 wb = *(const float4*)&wr[lane * 16 + q * 8 + 4];
      p0 += (double)xr[q * 8 + 0] * wa.x + (double)xr[q * 8 + 1] * wa.y
          + (double)xr[q * 8 + 2] * wa.z + (double)xr[q * 8 + 3] * wa.w;
      p1 += (double)xr[q * 8 + 4] * wb.x + (double)xr[q * 8 + 5] * wb.y
          + (double)xr[q * 8 + 6] * wb.z + (double)xr[q * 8 + 7] * wb.w;
    }
    double part = p0 + p1;
#pragma unroll
    for (int off = 32; off > 0; off >>= 1) part += __shfl_down(part, off, 64);
    if (lane == 0) {
      double d = part + (double)benc[j];
      rex[c] = d > 0.0 ? d : 0.0;
    }
  }
  __syncthreads();

  for (int c = tid; c < nR; c += 256) {
    double vc = rex[c]; int ic = ridx[c];
    int rank = 0;
    for (int c2 = 0; c2 < nR; ++c2) {
      double v2 = rex[c2];
      rank += (v2 > vc) || (v2 == vc && ridx[c2] < ic);
    }
    if (rank < rNeed) {
      int p = atomicAdd(&selCount, 1);
      vals[row * 64 + p] = (float)vc;
      idxs[row * 64 + p] = ic;
    }
  }
}

// ---------------------------------------------------------------------------
// Kernel 4: y = b_dec + sum_j vals[j]*W_dec[idx[j],:]  (bf16 gathers, fp32 out)
// ---------------------------------------------------------------------------
__global__ __launch_bounds__(256) void decode_kernel(
    const float* __restrict__ vals, const int* __restrict__ idxs,
    const ushort_t* __restrict__ Wdec_bf, const float* __restrict__ bdec,
    float* __restrict__ Y) {
  __shared__ float sv[2][TOPK];
  __shared__ int   si[2][TOPK];
  const int tid = threadIdx.x;
  const int r0  = blockIdx.x * 2;
  if (tid < 128) {
    int rr = tid >> 6, jj = tid & 63;
    sv[rr][jj] = vals[(r0 + rr) * 64 + jj];
    si[rr][jj] = idxs[(r0 + rr) * 64 + jj];
  }
  __syncthreads();
  const int rr  = tid >> 7;
  const int c0  = (tid & 127) * 8;
  const int row = r0 + rr;
  float4 b0 = *(const float4*)&bdec[c0];
  float4 b1 = *(const float4*)&bdec[c0 + 4];
  float a[8] = {b0.x, b0.y, b0.z, b0.w, b1.x, b1.y, b1.z, b1.w};
#pragma unroll 8
  for (int j = 0; j < TOPK; ++j) {
    const float vj = sv[rr][j];
    ushort8 w = *(const ushort8*)&Wdec_bf[(size_t)si[rr][j] * D_MODEL + c0];
#pragma unroll
    for (int u = 0; u < 8; ++u) a[u] += vj * bf2f(w[u]);
  }
  *(float4*)&Y[(size_t)row * D_MODEL + c0]     = (float4){a[0], a[1], a[2], a[3]};
  *(float4*)&Y[(size_t)row * D_MODEL + c0 + 4] = (float4){a[4], a[5], a[6], a[7]};
}

// ---------------------------------------------------------------------------
extern "C" void kernel_launch(void* const* d_in, const int* in_sizes, int n_in,
                              void* d_out, int out_size, void* d_ws, size_t ws_size,
                              hipStream_t stream) {
  const float* x     = (const float*)d_in[0];
  const float* W_enc = (const float*)d_in[1];
  const float* b_enc = (const float*)d_in[2];
  const float* W_dec = (const float*)d_in[3];
  const float* b_dec = (const float*)d_in[4];

  const size_t WT_BYTES   = (size_t)D_HIDDEN * D_MODEL * sizeof(ushort_t); // 32 MB
  const size_t WT32_BYTES = (size_t)D_HIDDEN * D_MODEL * sizeof(float);    // 64 MB
  const size_t XB_BYTES   = (size_t)N_TOKENS * D_MODEL * sizeof(ushort_t); //  8 MB
  const size_t V_BYTES    = (size_t)N_TOKENS * TOPK * sizeof(float);       //  1 MB
  const size_t F_BYTES    = (size_t)N_TOKENS * sizeof(int);                // 16 KB
  const size_t CAND_BYTES = (size_t)N_TOKENS * 128 * 64;                   // 32 MB
  const size_t FIXED      = WT_BYTES + WT32_BYTES + XB_BYTES + 2 * V_BYTES
                          + F_BYTES + CAND_BYTES;                          // ~138 MB

  int chunk_rows = 4096;  // bf16 Z chunk: 128 MB -> total ~266 MB; auto-shrink
  while (chunk_rows > 128 &&
         FIXED + (size_t)chunk_rows * D_HIDDEN * sizeof(ushort_t) > ws_size)
    chunk_rows >>= 1;

  char* ws = (char*)d_ws;
  size_t off = 0;
  ushort_t* WT    = (ushort_t*)(ws + off); off += WT_BYTES;
  float*    WT32  = (float*)(ws + off);    off += WT32_BYTES;
  ushort_t* XB    = (ushort_t*)(ws + off); off += XB_BYTES;
  float*    vals  = (float*)(ws + off);    off += V_BYTES;
  int*      idxs  = (int*)(ws + off);      off += V_BYTES;
  int*      flags = (int*)(ws + off);      off += F_BYTES;
  uint_t*   cand  = (uint_t*)(ws + off);   off += CAND_BYTES;
  ushort_t* Z     = (ushort_t*)(ws + off);
  float*    Y     = (float*)d_out;

  cast_x_kernel<<<dim3(N_TOKENS * D_MODEL / 1024), 256, 0, stream>>>(x, XB);
  transpose_cast_kernel<<<dim3(D_HIDDEN / 64, D_MODEL / 64), 256, 0, stream>>>(
      W_enc, WT, WT32);

  for (int r0 = 0; r0 < N_TOKENS; r0 += chunk_rows) {
    encode_gemm<<<dim3(D_HIDDEN / 128, chunk_rows / 128), 256, 0, stream>>>(
        XB + (size_t)r0 * D_MODEL, WT, b_enc, Z, cand + (size_t)r0 * 128 * 16);
    topk_select_kernel<<<dim3(chunk_rows), 256, 0, stream>>>(
        cand + (size_t)r0 * 128 * 16, x + (size_t)r0 * D_MODEL, WT32, b_enc,
        vals + (size_t)r0 * TOPK, idxs + (size_t)r0 * TOPK, flags + r0);
    topk_fallback_kernel<<<dim3(chunk_rows), 256, 0, stream>>>(
        flags + r0, Z, x + (size_t)r0 * D_MODEL, WT32, b_enc,
        vals + (size_t)r0 * TOPK, idxs + (size_t)r0 * TOPK);
  }

  cast_wdec_kernel<<<dim3(D_HIDDEN * D_MODEL / (256 * 8)), 256, 0, stream>>>(W_dec, WT);

  decode_kernel<<<dim3(N_TOKENS / 2), 256, 0, stream>>>(vals, idxs, WT, b_dec, Y);
}

// Round 9
// 582.801 us; speedup vs baseline: 1.1481x; 1.1481x over previous
//
#include <hip/hip_runtime.h>

typedef unsigned short ushort_t;
typedef unsigned short ushort8 __attribute__((ext_vector_type(8)));
typedef __bf16 bf16x8 __attribute__((ext_vector_type(8)));
typedef float f32x4 __attribute__((ext_vector_type(4)));
typedef unsigned int uint_t;

#define N_TOKENS 4096
#define D_MODEL  1024
#define D_HIDDEN 16384
#define TOPK     64
#define DELTA    0.03f   // >= 2*E, E = bf16-GEMM err (~5e-3) + bf16 quant (~4e-3)
#define RCAP     128     // max refine candidates per row (measured avg ~5)
#define T0SEL    1.25f   // candidate threshold; E[count]~249/row (sd~29), v64~1.85
#define CAP      512     // candidate list capacity per row (9-sigma margin)
#define SSL      15      // slots per (row, 128-col segment); P(overflow) ~ 1e-9

__device__ __forceinline__ float bf2f(ushort_t u) {
  union { unsigned u; float f; } c; c.u = ((unsigned)u) << 16; return c.f;
}
__device__ __forceinline__ ushort_t f2bf(float f) {
  union { float f; unsigned u; } c; c.f = f;
  unsigned x = c.u;
  unsigned r = (x + 0x7FFFu + ((x >> 16) & 1u)) >> 16;  // RNE
  return (ushort_t)r;
}

typedef __attribute__((address_space(1))) void GV;
typedef __attribute__((address_space(3))) void LV;
__device__ __forceinline__ void llds16(const void* g, void* l) {
  __builtin_amdgcn_global_load_lds((GV*)g, (LV*)l, 16, 0, 0);
}

// ---------------------------------------------------------------------------
// Kernel 0: cast x fp32 -> bf16
// ---------------------------------------------------------------------------
__global__ __launch_bounds__(256) void cast_x_kernel(
    const float* __restrict__ in, ushort_t* __restrict__ out) {
  const int i = (blockIdx.x * 256 + threadIdx.x) * 4;
  float4 v = *(const float4*)&in[i];
  ushort4 o;
  o.x = f2bf(v.x); o.y = f2bf(v.y); o.z = f2bf(v.z); o.w = f2bf(v.w);
  *(ushort4*)&out[i] = o;
}

// ---------------------------------------------------------------------------
// Kernel 0b: cast W_dec fp32 [H][K] -> bf16 (into WT buffer after fallback)
// ---------------------------------------------------------------------------
__global__ __launch_bounds__(256) void cast_wdec_kernel(
    const float* __restrict__ in, ushort_t* __restrict__ out) {
  const int i = (blockIdx.x * 256 + threadIdx.x) * 8;
  float4 v0 = *(const float4*)&in[i];
  float4 v1 = *(const float4*)&in[i + 4];
  ushort8 o;
  o[0] = f2bf(v0.x); o[1] = f2bf(v0.y); o[2] = f2bf(v0.z); o[3] = f2bf(v0.w);
  o[4] = f2bf(v1.x); o[5] = f2bf(v1.y); o[6] = f2bf(v1.z); o[7] = f2bf(v1.w);
  *(ushort8*)&out[i] = o;
}

// ---------------------------------------------------------------------------
// Kernel 1: W_enc fp32 [D_MODEL][D_HIDDEN] -> bf16 WT [H][K] + fp32 WT32 [H][K]
// ---------------------------------------------------------------------------
__global__ __launch_bounds__(256) void transpose_cast_kernel(
    const float* __restrict__ in, ushort_t* __restrict__ outb,
    float* __restrict__ out32) {
  __shared__ float tile[64][68];
  const int tid = threadIdx.x;
  const int n0 = blockIdx.x * 64;
  const int k0 = blockIdx.y * 64;
#pragma unroll
  for (int i = 0; i < 4; ++i) {
    int e = i * 256 + tid;
    int kk = e >> 4;
    int nn = (e & 15) * 4;
    float4 v = *(const float4*)&in[(size_t)(k0 + kk) * D_HIDDEN + n0 + nn];
    tile[kk][nn + 0] = v.x;
    tile[kk][nn + 1] = v.y;
    tile[kk][nn + 2] = v.z;
    tile[kk][nn + 3] = v.w;
  }
  __syncthreads();
#pragma unroll
  for (int i = 0; i < 4; ++i) {
    int e = i * 256 + tid;
    int nn = e >> 4;
    int kk = (e & 15) * 4;
    float4 f;
    f.x = tile[kk + 0][nn];
    f.y = tile[kk + 1][nn];
    f.z = tile[kk + 2][nn];
    f.w = tile[kk + 3][nn];
    *(float4*)&out32[(size_t)(n0 + nn) * D_MODEL + k0 + kk] = f;
    ushort4 b;
    b.x = f2bf(f.x); b.y = f2bf(f.y); b.z = f2bf(f.z); b.w = f2bf(f.w);
    *(ushort4*)&outb[(size_t)(n0 + nn) * D_MODEL + k0 + kk] = b;
  }
}

// ---------------------------------------------------------------------------
// Kernel 2 (R15): relu(x @ W_enc + b_enc) -> candidates ONLY (Z deleted).
// Main loop byte-identical to the verified form. Epilogue: per-row LDS
// compaction (aliasing As/Bs), then tid<128 writes one 64B record into a
// WRITER-CONTIGUOUS region: record(cb,row) = cand[cb*N_TOKENS + row].
// Block writes 128 consecutive records = 8KB fully-owned cache lines ->
// zero false sharing (R14's +62us came from 64B half-line sharing between
// adjacent cb blocks; R9/R11 from atomics/partial lines).
// ---------------------------------------------------------------------------
__global__ __launch_bounds__(256) void encode_gemm(
    const ushort_t* __restrict__ X, const ushort_t* __restrict__ WT,
    const float* __restrict__ benc, uint_t* __restrict__ cand) {
  __shared__ ushort_t As[128 * 32];
  __shared__ ushort_t Bs[128 * 32];
  const int tid  = threadIdx.x;
  const int wave = tid >> 6, lane = tid & 63;
  const int m0 = blockIdx.y * 128;
  const int n0 = blockIdx.x * 128;
  const int wm = (wave >> 1) * 64;
  const int wn = (wave & 1) * 64;
  const int lr = lane >> 2;
  const int lk = (lane & 3) * 8;

  f32x4 acc[4][4];
#pragma unroll
  for (int i = 0; i < 4; ++i)
#pragma unroll
    for (int j = 0; j < 4; ++j) acc[i][j] = (f32x4){0.f, 0.f, 0.f, 0.f};

  for (int k0 = 0; k0 < D_MODEL; k0 += 32) {
    __syncthreads();
#pragma unroll
    for (int c = 0; c < 2; ++c) {
      const int chunk = c * 4 + wave;
      const int m = chunk * 16 + lr;
      llds16(&X [(size_t)(m0 + m) * D_MODEL + k0 + lk], &As[chunk * 512]);
      llds16(&WT[(size_t)(n0 + m) * D_MODEL + k0 + lk], &Bs[chunk * 512]);
    }
    __syncthreads();
    bf16x8 af[4], bfr[4];
#pragma unroll
    for (int t = 0; t < 4; ++t) {
      af[t]  = *(const bf16x8*)&As[(wm + t * 16 + (lane & 15)) * 32 + (lane >> 4) * 8];
      bfr[t] = *(const bf16x8*)&Bs[(wn + t * 16 + (lane & 15)) * 32 + (lane >> 4) * 8];
    }
#pragma unroll
    for (int mt = 0; mt < 4; ++mt)
#pragma unroll
      for (int nt = 0; nt < 4; ++nt)
        acc[mt][nt] = __builtin_amdgcn_mfma_f32_16x16x32_bf16(
            af[mt], bfr[nt], acc[mt][nt], 0, 0, 0);
  }

  // ---- epilogue: LDS candidate compaction (aliases As/Bs) ----
  uint_t* slots = (uint_t*)As;     // 128 rows x 15 slots x 4B = 7680B
  int*    lcnt  = (int*)Bs;        // 128 x 4B
  __syncthreads();                 // all waves done reading As/Bs
  if (tid < 128) lcnt[tid] = 0;
  __syncthreads();

  const int col_base  = n0 + wn + (lane & 15);
  const int lcol_base = wn + (lane & 15);
  const int lrow_base = wm + (lane >> 4) * 4;
#pragma unroll
  for (int nt = 0; nt < 4; ++nt) {
    const float bias = benc[col_base + nt * 16];
#pragma unroll
    for (int mt = 0; mt < 4; ++mt) {
#pragma unroll
      for (int r = 0; r < 4; ++r) {
        float v = acc[mt][nt][r] + bias;
        if (v > T0SEL) {
          const int lrw = lrow_base + mt * 16 + r;          // 0..127
          int p = atomicAdd(&lcnt[lrw], 1);
          if (p < SSL)
            slots[lrw * SSL + p] =
                ((uint_t)f2bf(v) << 16) | (uint_t)(lcol_base + nt * 16);
        }
      }
    }
  }
  __syncthreads();

  if (tid < 128) {
    const int c = lcnt[tid];                 // raw count; >SSL => poison
    const uint_t* s = &slots[tid * SSL];
    uint4 w0 = {s[0],  s[1],  s[2],  s[3]};
    uint4 w1 = {s[4],  s[5],  s[6],  s[7]};
    uint4 w2 = {s[8],  s[9],  s[10], s[11]};
    uint4 w3 = {s[12], s[13], s[14], (uint_t)c};
    // writer-contiguous: this block owns records [cb*N + m0, cb*N + m0+127]
    uint_t* dst = cand + ((size_t)blockIdx.x * N_TOKENS + m0 + tid) * 16;
    ((uint4*)dst)[0] = w0;
    ((uint4*)dst)[1] = w1;
    ((uint4*)dst)[2] = w2;
    ((uint4*)dst)[3] = w3;
  }
}

// ---------------------------------------------------------------------------
// Kernel 3: select from candidate records. One block/row reads 128 scattered
// 64B records (stride N_TOKENS*64B; row-adjacent blocks share 128B lines via
// L3), scan+scatter to LDS, then the VERBATIM verified machinery: exact v64
// by (value desc, idx asc), DELTA band, fp64 refine via WT32.
// Bails (flag=1) on segment overflow / n<64 / n>CAP / v64 near T0SEL.
// ---------------------------------------------------------------------------
__global__ __launch_bounds__(256) void topk_select_kernel(
    const uint_t* __restrict__ cand, const float* __restrict__ x32,
    const float* __restrict__ WT32, const float* __restrict__ benc,
    float* __restrict__ vals, int* __restrict__ idxs, int* __restrict__ flags) {
  __shared__ float  sval[CAP];
  __shared__ int    sidx[CAP];
  __shared__ int    wsum[2];
  __shared__ int    ridx[RCAP];
  __shared__ double rex[RCAP];
  __shared__ float  sV64;
  __shared__ int    selCount, refCount, sOver;
  const int tid  = threadIdx.x;
  const int lane = tid & 63;
  const int wv   = tid >> 6;
  const int row  = blockIdx.x;

  // issue the candidate-record loads up front (tid<128: one 64B record each)
  uint4 e0, e1, e2, e3;
  if (tid < 128) {
    const uint_t* seg = cand + ((size_t)tid * N_TOKENS + row) * 16;
    e0 = ((const uint4*)seg)[0];
    e1 = ((const uint4*)seg)[1];
    e2 = ((const uint4*)seg)[2];
    e3 = ((const uint4*)seg)[3];
  }
  if (tid == 0) { selCount = 0; refCount = 0; sOver = 0; }
  __syncthreads();

  int myc = 0;
  if (tid < 128) {
    myc = (int)e3.w;
    if (myc > SSL) sOver = 1;     // lost candidates in this segment
  }
  const int valid = (tid < 128) ? min(myc, SSL) : 0;

  // inclusive scan within wave (waves 0,1 carry data; 2,3 idle)
  int inc = valid;
#pragma unroll
  for (int off = 1; off < 64; off <<= 1) {
    int y = __shfl_up(inc, off, 64);
    if (lane >= off) inc += y;
  }
  if (lane == 63 && wv < 2) wsum[wv] = inc;
  __syncthreads();
  const int base = inc - valid + ((wv == 1) ? wsum[0] : 0);
  const int n = wsum[0] + wsum[1];
  if (sOver || n < TOPK || n > CAP) { if (tid == 0) flags[row] = 1; return; }

  // scatter (static indices only — rule #20)
#define EMIT(k, pv)                                                       \
  if ((k) < valid) {                                                      \
    const uint_t p = (pv);                                                \
    const int q = base + (k);                                             \
    sval[q] = bf2f((ushort_t)(p >> 16));                                  \
    sidx[q] = (tid << 7) | (int)(p & 0x7Fu);                              \
  }
  if (tid < 128) {
    EMIT(0, e0.x)  EMIT(1, e0.y)  EMIT(2, e0.z)  EMIT(3, e0.w)
    EMIT(4, e1.x)  EMIT(5, e1.y)  EMIT(6, e1.z)  EMIT(7, e1.w)
    EMIT(8, e2.x)  EMIT(9, e2.y)  EMIT(10, e2.z) EMIT(11, e2.w)
    EMIT(12, e3.x) EMIT(13, e3.y) EMIT(14, e3.z)
  }
#undef EMIT
  __syncthreads();

  // ---- exact 64th by (value desc, index asc); LDS reads are broadcasts ----
  for (int j = tid; j < n; j += 256) {
    float vj = sval[j]; int ij = sidx[j];
    int rank = 0;
    for (int j2 = 0; j2 < n; ++j2) {
      float v2 = sval[j2];
      rank += (v2 > vj) || (v2 == vj && sidx[j2] < ij);
    }
    if (rank == TOPK - 1) sV64 = vj;
  }
  __syncthreads();
  const float v64 = sV64;
  if (v64 <= T0SEL + DELTA) { if (tid == 0) flags[row] = 1; return; }

  // ---- classify: sure-selects vs refine band ----
  for (int j = tid; j < n; j += 256) {
    float v = sval[j];
    if (v > v64 + DELTA) {
      int p2 = atomicAdd(&selCount, 1);
      vals[(size_t)row * TOPK + p2] = v;
      idxs[(size_t)row * TOPK + p2] = sidx[j];
    } else if (v >= v64 - DELTA) {
      int c = atomicAdd(&refCount, 1);
      if (c < RCAP) ridx[c] = sidx[j];
    }
  }
  __syncthreads();
  if (refCount > RCAP) { if (tid == 0) flags[row] = 1; return; }
  if (tid == 0) flags[row] = 0;
  const int nS = selCount;
  const int nR = refCount;
  const int rNeed = TOPK - nS;

  // ---- Phase D: exact fp64 dots, one wave per candidate ----
  float xr[16];
  {
    const float* xrb = &x32[(size_t)row * D_MODEL + lane * 16];
#pragma unroll
    for (int q = 0; q < 4; ++q)
      *(float4*)&xr[q * 4] = *(const float4*)&xrb[q * 4];
  }
  for (int c = wv; c < nR; c += 4) {
    const int j = ridx[c];
    const float* wr = &WT32[(size_t)j * D_MODEL];
    double p0 = 0.0, p1 = 0.0;
#pragma unroll
    for (int q = 0; q < 2; ++q) {
      const float4 wa = *(const float4*)&wr[lane * 16 + q * 8];
      const float4 wb = *(const float4*)&wr[lane * 16 + q * 8 + 4];
      p0 += (double)xr[q * 8 + 0] * wa.x + (double)xr[q * 8 + 1] * wa.y
          + (double)xr[q * 8 + 2] * wa.z + (double)xr[q * 8 + 3] * wa.w;
      p1 += (double)xr[q * 8 + 4] * wb.x + (double)xr[q * 8 + 5] * wb.y
          + (double)xr[q * 8 + 6] * wb.z + (double)xr[q * 8 + 7] * wb.w;
    }
    double part = p0 + p1;
#pragma unroll
    for (int off = 32; off > 0; off >>= 1) part += __shfl_down(part, off, 64);
    if (lane == 0) {
      double d = part + (double)benc[j];
      rex[c] = d > 0.0 ? d : 0.0;
    }
  }
  __syncthreads();

  // ---- Phase E: rank refined by (value desc, index asc), take top rNeed ----
  for (int c = tid; c < nR; c += 256) {
    double vc = rex[c]; int ic = ridx[c];
    int rank = 0;
    for (int c2 = 0; c2 < nR; ++c2) {
      double v2 = rex[c2];
      rank += (v2 > vc) || (v2 == vc && ridx[c2] < ic);
    }
    if (rank < rNeed) {
      int p2 = atomicAdd(&selCount, 1);
      vals[(size_t)row * TOPK + p2] = (float)vc;
      idxs[(size_t)row * TOPK + p2] = ic;
    }
  }
}

// ---------------------------------------------------------------------------
// Kernel 3b: fallback — recompute the row's pre-activations into LDS (bf16,
// fp32 accumulate from bf16 inputs, error bounded like the GEMM path), then
// run the VERBATIM verified full-row selection body. Runs only for flagged
// rows (9-sigma events; statistically never) — perf irrelevant, correctness
// insurance for arbitrary inputs.
// ---------------------------------------------------------------------------
__global__ __launch_bounds__(256) void topk_fallback_kernel(
    const int* __restrict__ flags, const ushort_t* __restrict__ XB,
    const ushort_t* __restrict__ WT, const float* __restrict__ x32,
    const float* __restrict__ WT32, const float* __restrict__ benc,
    float* __restrict__ vals, int* __restrict__ idxs) {
  if (flags[blockIdx.x] == 0) return;
  __shared__ ushort_t zrow[D_HIDDEN];       // 32 KB
  __shared__ ushort_t xb[D_MODEL];          //  2 KB
  __shared__ int hist[512 * 9 + 32];        // ~18.6 KB (overlaid below)
  float*  cval = (float*)hist;                 // [512]
  int*    cidx = (int*)hist + 512;             // [512]
  int*    ridx = (int*)hist + 1024;            // [RCAP]
  double* rex  = (double*)((int*)hist + 1156); // [RCAP]
  __shared__ int   wtot[4];
  __shared__ int   sTbin, sAbove, selCount, candCount, refCount;
  __shared__ float sV64;

  const int tid  = threadIdx.x;
  const int wave = tid >> 6, lane = tid & 63;
  const int row  = blockIdx.x;

  // ---- phase 0: recompute z~ row into LDS ----
  *(ushort4*)&xb[tid * 4] = *(const ushort4*)&XB[(size_t)row * D_MODEL + tid * 4];
  __syncthreads();
  for (int c = 0; c < 64; ++c) {
    const int j = c * 256 + tid;
    const ushort_t* wr = &WT[(size_t)j * D_MODEL];
    float acc = 0.0f;
    for (int kb = 0; kb < D_MODEL; kb += 8) {
      ushort8 w = *(const ushort8*)&wr[kb];
#pragma unroll
      for (int u = 0; u < 8; ++u) acc += bf2f(xb[kb + u]) * bf2f(w[u]);
    }
    zrow[j] = f2bf(fmaxf(acc + benc[j], 0.0f));
  }
  __syncthreads();

  // ---- verified full-row selection body (source = LDS zrow) ----
  ushort8 u8v[8];
#pragma unroll
  for (int i = 0; i < 8; ++i) u8v[i] = *(const ushort8*)&zrow[i * 2048 + tid * 8];
#define ZIDX(i, j) ((i) * 2048 + tid * 8 + (j))

  for (int k = tid; k < 512 * 9; k += 256) hist[k] = 0;
  if (tid == 0) { sTbin = -1; selCount = 0; candCount = 0; refCount = 0; }
  __syncthreads();

  const int cpy = lane & 7;
#pragma unroll
  for (int i = 0; i < 8; ++i)
#pragma unroll
    for (int j = 0; j < 8; ++j) {
      ushort_t w = u8v[i][j];
      if (w) atomicAdd(&hist[((int)(w >> 6)) * 9 + cpy], 1);
    }
  __syncthreads();

  int h0 = 0, h1 = 0;
#pragma unroll
  for (int c = 0; c < 8; ++c) {
    int cc = (tid + c) & 7;
    h0 += hist[(2 * tid) * 9 + cc];
    h1 += hist[(2 * tid + 1) * 9 + cc];
  }
  const int s = h0 + h1;
  int x = s;
#pragma unroll
  for (int off = 1; off < 64; off <<= 1) {
    int y = __shfl_down(x, off, 64);
    if (lane + off < 64) x += y;
  }
  if (lane == 0) wtot[wave] = x;
  __syncthreads();
  int cross = 0;
  if (wave < 3) cross += wtot[3];
  if (wave < 2) cross += wtot[2];
  if (wave < 1) cross += wtot[1];
  const int Sexc = cross + x - s;
  if (Sexc < TOPK && Sexc + h1 >= TOPK) { sTbin = 2 * tid + 1; sAbove = Sexc; }
  const int c0 = Sexc + h1;
  if (c0 < TOPK && c0 + h0 >= TOPK) { sTbin = 2 * tid; sAbove = c0; }
  __syncthreads();
  const int Tbin = sTbin, nAbove = sAbove;

  if (Tbin < 0) {
#pragma unroll
    for (int i = 0; i < 8; ++i)
#pragma unroll
      for (int j = 0; j < 8; ++j) {
        ushort_t w = u8v[i][j];
        if (w) {
          int p = atomicAdd(&selCount, 1);
          if (p < TOPK) { vals[row * 64 + p] = bf2f(w); idxs[row * 64 + p] = ZIDX(i, j); }
        }
      }
    __syncthreads();
    for (int p2 = min(selCount, TOPK) + tid; p2 < TOPK; p2 += 256) {
      vals[row * 64 + p2] = 0.0f; idxs[row * 64 + p2] = 0;
    }
    return;
  }

#pragma unroll
  for (int i = 0; i < 8; ++i)
#pragma unroll
    for (int j = 0; j < 8; ++j) {
      ushort_t w = u8v[i][j];
      if (w && (int)(w >> 6) == Tbin) {
        int c = atomicAdd(&candCount, 1);
        if (c < 512) { cval[c] = bf2f(w); cidx[c] = ZIDX(i, j); }
      }
    }
  __syncthreads();
  {
    const int r  = TOPK - nAbove;
    const int nc = min(candCount, 512);
    for (int j = tid; j < nc; j += 256) {
      float vj = cval[j]; int ij = cidx[j];
      int rank = 0;
      for (int j2 = 0; j2 < nc; ++j2) {
        float v2 = cval[j2];
        rank += (v2 > vj) || (v2 == vj && cidx[j2] < ij);
      }
      if (rank == r - 1) sV64 = vj;
    }
  }
  __syncthreads();
  const float v64 = sV64;

#pragma unroll
  for (int i = 0; i < 8; ++i)
#pragma unroll
    for (int j = 0; j < 8; ++j) {
      ushort_t w = u8v[i][j];
      if (!w) continue;
      float v = bf2f(w);
      if (v > v64 + DELTA) {
        int p = atomicAdd(&selCount, 1);
        vals[row * 64 + p] = v;
        idxs[row * 64 + p] = ZIDX(i, j);
      } else if (v >= v64 - DELTA) {
        int c = atomicAdd(&refCount, 1);
        if (c < RCAP) ridx[c] = ZIDX(i, j);
      }
    }
  __syncthreads();
  const int nS = selCount;
  const int nR = min(refCount, RCAP);
  const int rNeed = TOPK - nS;

  float xr[16];
  {
    const float* xrb = &x32[(size_t)row * D_MODEL + lane * 16];
#pragma unroll
    for (int q = 0; q < 4; ++q)
      *(float4*)&xr[q * 4] = *(const float4*)&xrb[q * 4];
  }
  for (int c = wave; c < nR; c += 4) {
    const int j = ridx[c];
    const float* wr = &WT32[(size_t)j * D_MODEL];
    double p0 = 0.0, p1 = 0.0;
#pragma unroll
    for (int q = 0; q < 2; ++q) {
      const float4 wa = *(const float4*)&wr[lane * 16 + q * 8];
      const float4 wb = *(const float4*)&wr[lane * 16 + q * 8 + 4];
      p0 += (double)xr[q * 8 + 0] * wa.x + (double)xr[q * 8 + 1] * wa.y
          + (double)xr[q * 8 + 2] * wa.z + (double)xr[q * 8 + 3] * wa.w;
      p1 += (double)xr[q * 8 + 4] * wb.x + (double)xr[q * 8 + 5] * wb.y
          + (double)xr[q * 8 + 6] * wb.z + (double)xr[q * 8 + 7] * wb.w;
    }
    double part = p0 + p1;
#pragma unroll
    for (int off = 32; off > 0; off >>= 1) part += __shfl_down(part, off, 64);
    if (lane == 0) {
      double d = part + (double)benc[j];
      rex[c] = d > 0.0 ? d : 0.0;
    }
  }
  __syncthreads();

  for (int c = tid; c < nR; c += 256) {
    double vc = rex[c]; int ic = ridx[c];
    int rank = 0;
    for (int c2 = 0; c2 < nR; ++c2) {
      double v2 = rex[c2];
      rank += (v2 > vc) || (v2 == vc && ridx[c2] < ic);
    }
    if (rank < rNeed) {
      int p = atomicAdd(&selCount, 1);
      vals[row * 64 + p] = (float)vc;
      idxs[row * 64 + p] = ic;
    }
  }
}

// ---------------------------------------------------------------------------
// Kernel 4: y = b_dec + sum_j vals[j]*W_dec[idx[j],:]  (bf16 gathers, fp32 out)
// ---------------------------------------------------------------------------
__global__ __launch_bounds__(256) void decode_kernel(
    const float* __restrict__ vals, const int* __restrict__ idxs,
    const ushort_t* __restrict__ Wdec_bf, const float* __restrict__ bdec,
    float* __restrict__ Y) {
  __shared__ float sv[2][TOPK];
  __shared__ int   si[2][TOPK];
  const int tid = threadIdx.x;
  const int r0  = blockIdx.x * 2;
  if (tid < 128) {
    int rr = tid >> 6, jj = tid & 63;
    sv[rr][jj] = vals[(r0 + rr) * 64 + jj];
    si[rr][jj] = idxs[(r0 + rr) * 64 + jj];
  }
  __syncthreads();
  const int rr  = tid >> 7;
  const int c0  = (tid & 127) * 8;
  const int row = r0 + rr;
  float4 b0 = *(const float4*)&bdec[c0];
  float4 b1 = *(const float4*)&bdec[c0 + 4];
  float a[8] = {b0.x, b0.y, b0.z, b0.w, b1.x, b1.y, b1.z, b1.w};
#pragma unroll 8
  for (int j = 0; j < TOPK; ++j) {
    const float vj = sv[rr][j];
    ushort8 w = *(const ushort8*)&Wdec_bf[(size_t)si[rr][j] * D_MODEL + c0];
#pragma unroll
    for (int u = 0; u < 8; ++u) a[u] += vj * bf2f(w[u]);
  }
  *(float4*)&Y[(size_t)row * D_MODEL + c0]     = (float4){a[0], a[1], a[2], a[3]};
  *(float4*)&Y[(size_t)row * D_MODEL + c0 + 4] = (float4){a[4], a[5], a[6], a[7]};
}

// ---------------------------------------------------------------------------
extern "C" void kernel_launch(void* const* d_in, const int* in_sizes, int n_in,
                              void* d_out, int out_size, void* d_ws, size_t ws_size,
                              hipStream_t stream) {
  const float* x     = (const float*)d_in[0];
  const float* W_enc = (const float*)d_in[1];
  const float* b_enc = (const float*)d_in[2];
  const float* W_dec = (const float*)d_in[3];
  const float* b_dec = (const float*)d_in[4];

  const size_t WT_BYTES   = (size_t)D_HIDDEN * D_MODEL * sizeof(ushort_t); // 32 MB
  const size_t WT32_BYTES = (size_t)D_HIDDEN * D_MODEL * sizeof(float);    // 64 MB
  const size_t XB_BYTES   = (size_t)N_TOKENS * D_MODEL * sizeof(ushort_t); //  8 MB
  const size_t V_BYTES    = (size_t)N_TOKENS * TOPK * sizeof(float);       //  1 MB
  const size_t F_BYTES    = (size_t)N_TOKENS * sizeof(int);                // 16 KB
  const size_t CAND_BYTES = (size_t)N_TOKENS * 128 * 64;                   // 32 MB
  // total ~138 MB; no Z buffer, no chunking.

  char* ws = (char*)d_ws;
  size_t off = 0;
  ushort_t* WT    = (ushort_t*)(ws + off); off += WT_BYTES;
  float*    WT32  = (float*)(ws + off);    off += WT32_BYTES;
  ushort_t* XB    = (ushort_t*)(ws + off); off += XB_BYTES;
  float*    vals  = (float*)(ws + off);    off += V_BYTES;
  int*      idxs  = (int*)(ws + off);      off += V_BYTES;
  int*      flags = (int*)(ws + off);      off += F_BYTES;
  uint_t*   cand  = (uint_t*)(ws + off);   off += CAND_BYTES;
  float*    Y     = (float*)d_out;

  cast_x_kernel<<<dim3(N_TOKENS * D_MODEL / 1024), 256, 0, stream>>>(x, XB);
  transpose_cast_kernel<<<dim3(D_HIDDEN / 64, D_MODEL / 64), 256, 0, stream>>>(
      W_enc, WT, WT32);

  encode_gemm<<<dim3(D_HIDDEN / 128, N_TOKENS / 128), 256, 0, stream>>>(
      XB, WT, b_enc, cand);
  topk_select_kernel<<<dim3(N_TOKENS), 256, 0, stream>>>(
      cand, x, WT32, b_enc, vals, idxs, flags);
  topk_fallback_kernel<<<dim3(N_TOKENS), 256, 0, stream>>>(
      flags, XB, WT, x, WT32, b_enc, vals, idxs);

  cast_wdec_kernel<<<dim3(D_HIDDEN * D_MODEL / (256 * 8)), 256, 0, stream>>>(W_dec, WT);

  decode_kernel<<<dim3(N_TOKENS / 2), 256, 0, stream>>>(vals, idxs, WT, b_dec, Y);
}